// Round 8
// baseline (130.580 us; speedup 1.0000x reference)
//
#include <hip/hip_runtime.h>

// Problem constants (match reference)
#define B_ 8
#define H_ 512
#define W_ 1024
#define HW_ (H_ * W_)
#define G_ 104857
#define TPT_ 4                              // triplets per thread
#define TILE_ (256 * TPT_)                  // 1024 triplets per block
#define TILES_ ((G_ + TILE_ - 1) / TILE_)   // 103
#define NBLK_ (TILES_ * B_)                 // 824
#define EPS_ 1e-6f
#define DCOS_ 0.867f
#define DDIFF_ 0.005f
#define DZ_ 1e-5f

// Count-only 256-bin histogram over loss in [0, 2*sqrt(3)=3.4641].
// Trimmed-quantile bin-center approximation: measured absmax 0.0 in R5-R7.
#define NBIN_ 256
#define BINSCALE_ 73.0f          // 3.4642*73 = 252.9 < 256

// Reduction kernel geometry
#define NRBLK_ 64
#define ROWS_PER_ ((NBLK_ + NRBLK_ - 1) / NRBLK_)   // 13

// ws layout. NO memset node: kernel1 writes bhist/bsum fully and block 0 of
// kernel1 zero-inits the small reduction scratch (kernel-boundary coherence).
#define OFF_BHIST 0                                  // NBLK_ x 256 u16
#define OFF_BSUM  (NBLK_ * NBIN_ * 2)                // NBLK_ f32
#define OFF_GBINS (OFF_BSUM + NBLK_ * 4)             // 256 u32
#define OFF_GSUM  (OFF_GBINS + NBIN_ * 4)            // f64 (8-aligned)
#define OFF_DONE  (OFF_GSUM + 8)                     // u32

struct F3 { float x, y, z; };
__device__ __forceinline__ F3 f3sub(F3 a, F3 b) { return {a.x - b.x, a.y - b.y, a.z - b.z}; }
__device__ __forceinline__ float f3dot(F3 a, F3 b) { return a.x * b.x + a.y * b.y + a.z * b.z; }
__device__ __forceinline__ F3 f3cross(F3 a, F3 b) {
    return {a.y * b.z - a.z * b.y, a.z * b.x - a.x * b.z, a.x * b.y - a.y * b.x};
}

// R7 structure, 4 triplets/thread: 12 coalesced index loads + 24 depth
// gathers all issued before any consumption. Kernel is gather-latency bound
// (VALU <20%, HBM <10% every round); MLP/wave is the binding resource
// (R6->R7: 2x MLP gave -8us). Loads are program-order, so triplet j's math
// overlaps the still-outstanding gathers of triplets j+1..3.
// blockIdx.x & 7 = image -> image's depth data stays on one XCD's L2.
// No global atomics; histogram leaves as coalesced non-atomic u16 store.
__global__ void __launch_bounds__(256)
compute_kernel(const float* __restrict__ pred, const float* __restrict__ targ,
               const float* __restrict__ intr,
               const int* __restrict__ p1, const int* __restrict__ p2,
               const int* __restrict__ p3,
               unsigned short* __restrict__ bhist, float* __restrict__ bsum,
               unsigned int* __restrict__ gbins, double* __restrict__ gsum,
               unsigned int* __restrict__ donecnt)
{
    __shared__ unsigned int hc[NBIN_];
    const int t = threadIdx.x;
    hc[t] = 0u;
    __syncthreads();

    const int img = blockIdx.x & 7;
    const int base = (blockIdx.x >> 3) * TILE_;

    const float fx = intr[img * 9 + 0];  // fx used for both x and y (per ref)
    const float u0 = intr[img * 9 + 2];
    const float v0 = intr[img * 9 + 5];
    const float invf = 1.0f / fx;
    const float* tb = targ + (size_t)img * HW_;
    const float* pb = pred + (size_t)img * HW_;
    const int goff = img * G_;

    // ---- all loads hoisted: 12 index loads, then 24 gathers in flight ----
    int i1[TPT_], i2[TPT_], i3[TPT_];
    bool inr[TPT_];
    float dt1[TPT_], dt2[TPT_], dt3[TPT_], dp1[TPT_], dp2[TPT_], dp3[TPT_];
#pragma unroll
    for (int j = 0; j < TPT_; ++j) {
        int g = base + j * 256 + t;
        inr[j] = g < G_;
        int gi = inr[j] ? (goff + g) : goff;   // clamp: index 0 is safe
        i1[j] = p1[gi]; i2[j] = p2[gi]; i3[j] = p3[gi];
    }
#pragma unroll
    for (int j = 0; j < TPT_; ++j) {
        dt1[j] = tb[i1[j]]; dt2[j] = tb[i2[j]]; dt3[j] = tb[i3[j]];
        dp1[j] = pb[i1[j]]; dp2[j] = pb[i2[j]]; dp3[j] = pb[i3[j]];
    }

    auto tri = [&](int a1, int a2, int a3, float T1, float T2, float T3,
                   float Q1, float Q2, float Q3, float& loss) -> bool {
        auto mk = [&](int i, float d) -> F3 {
            float u = (float)(i & (W_ - 1));
            float v = (float)(i >> 10);
            return F3{(u - u0) * d * invf, (v - v0) * d * invf, d};
        };
        F3 G1 = mk(a1, T1), G2 = mk(a2, T2), G3 = mk(a3, T3);
        F3 P1 = mk(a1, Q1), P2 = mk(a2, Q2), P3 = mk(a3, Q3);

        // ---- filter_mask on GT groups (division-free comparisons) ----
        F3 d12 = f3sub(G2, G1), d13 = f3sub(G3, G1), d23 = f3sub(G3, G2);
        float e11 = f3dot(d12, d12), e22 = f3dot(d13, d13), e33 = f3dot(d23, d23);
        float e12 = f3dot(d12, d13), e13 = f3dot(d12, d23), e23 = f3dot(d13, d23);
        float q1 = sqrtf(e11), q2 = sqrtf(e22), q3 = sqrtf(e33);
        int cnt = 0;
        cnt += (e11 > DCOS_ * (q1 * q1 + EPS_)) ? 1 : 0;
        cnt += (e22 > DCOS_ * (q2 * q2 + EPS_)) ? 1 : 0;
        cnt += (e33 > DCOS_ * (q3 * q3 + EPS_)) ? 1 : 0;
        cnt += (fabsf(e12) > DCOS_ * (q1 * q2 + EPS_)) ? 2 : 0;  // symmetric off-diag
        cnt += (fabsf(e13) > DCOS_ * (q1 * q3 + EPS_)) ? 2 : 0;
        cnt += (fabsf(e23) > DCOS_ * (q2 * q3 + EPS_)) ? 2 : 0;
        bool mask_cos = cnt > 3;
        bool mask_pad = (G1.z > DZ_) && (G2.z > DZ_) && (G3.z > DZ_);
        bool mx = (fabsf(d12.x) < DDIFF_) || (fabsf(d13.x) < DDIFF_) || (fabsf(d23.x) < DDIFF_);
        bool my = (fabsf(d12.y) < DDIFF_) || (fabsf(d13.y) < DDIFF_) || (fabsf(d23.y) < DDIFF_);
        bool mz = (fabsf(d12.z) < DDIFF_) || (fabsf(d13.z) < DDIFF_) || (fabsf(d23.z) < DDIFF_);
        bool valid = mask_pad && !((mx && my && mz) || mask_cos);
        if (!valid) { loss = 0.0f; return false; }

        // faithful replication of the reference's boolean-mask broadcast quirk
        bool c0 = (P1.z == 0.0f), c1 = (P2.z == 0.0f), c2 = (P3.z == 0.0f);
        if (c0) { P1.x = 1e-4f; P2.x = 1e-4f; P3.x = 1e-4f; }
        if (c1) { P1.y = 1e-4f; P2.y = 1e-4f; P3.y = 1e-4f; }
        if (c2) { P1.z = 1e-4f; P2.z = 1e-4f; P3.z = 1e-4f; }

        auto vnormal = [](F3 A, F3 Bp, F3 C) -> F3 {
            F3 a = f3sub(Bp, A), c = f3sub(C, A);
            F3 n = f3cross(a, c);
            float d = f3dot(n, n);
            float r = (d > 0.0f) ? rsqrtf(d) : 0.0f;  // n==0 -> 0/EPS==0 in ref
            return F3{n.x * r, n.y * r, n.z * r};
        };
        F3 ng = vnormal(G1, G2, G3);
        F3 nd = vnormal(P1, P2, P3);
        loss = fabsf(ng.x - nd.x) + fabsf(ng.y - nd.y) + fabsf(ng.z - nd.z);
        return true;
    };

    float lsum = 0.0f;
#pragma unroll
    for (int j = 0; j < TPT_; ++j) {
        float l;
        bool v = inr[j] && tri(i1[j], i2[j], i3[j], dt1[j], dt2[j], dt3[j],
                               dp1[j], dp2[j], dp3[j], l);
        if (v) {
            atomicAdd(&hc[min((int)(l * BINSCALE_), NBIN_ - 1)], 1u);
            lsum += l;
        }
    }

    // exact loss sum: wave shuffle -> block -> one f32 store (no atomics)
    for (int off = 32; off > 0; off >>= 1) lsum += __shfl_down(lsum, off, 64);
    __shared__ float wsum[4];
    if ((t & 63) == 0) wsum[t >> 6] = lsum;
    __syncthreads();
    if (t == 0) bsum[blockIdx.x] = wsum[0] + wsum[1] + wsum[2] + wsum[3];

    // non-atomic coalesced histogram dump (u16: block max count 1024 fits)
    bhist[(size_t)blockIdx.x * NBIN_ + t] = (unsigned short)hc[t];

    // block 0 zero-inits kernel2's scratch (kernel-boundary coherence)
    if (blockIdx.x == 0) {
        gbins[t] = 0u;
        if (t == 0) { *gsum = 0.0; *donecnt = 0u; }
    }
}

// 64 blocks: column-sum the 824x256 u16 block-histograms in registers
// (coalesced 512B rows, L2-resident), flush 16K well-spread global atomics;
// block 0 reduces the block sums; last-done block computes the trimmed mean.
__global__ void __launch_bounds__(256)
reduce_kernel(const unsigned short* __restrict__ bhist, const float* __restrict__ bsum,
              unsigned int* __restrict__ gbins, double* __restrict__ gsum,
              unsigned int* __restrict__ donecnt, float* __restrict__ out)
{
    const int t = threadIdx.x;
    const int r0 = blockIdx.x * ROWS_PER_;
    const int r1 = min(NBLK_, r0 + ROWS_PER_);
    unsigned int acc = 0;
    for (int r = r0; r < r1; ++r) acc += (unsigned int)bhist[(size_t)r * NBIN_ + t];
    if (acc) atomicAdd(&gbins[t], acc);

    if (blockIdx.x == 0) {  // exact total sum
        double ls = 0.0;
        for (int i = t; i < NBLK_; i += 256) ls += (double)bsum[i];
        for (int off = 32; off > 0; off >>= 1) ls += __shfl_down(ls, off, 64);
        __shared__ double ws[4];
        if ((t & 63) == 0) ws[t >> 6] = ls;
        __syncthreads();
        if (t == 0) atomicAdd(gsum, ws[0] + ws[1] + ws[2] + ws[3]);
    }

    __shared__ unsigned int lastFlag;
    __syncthreads();
    if (t == 0) {
        __threadfence();
        lastFlag = (atomicAdd(donecnt, 1u) == (unsigned int)(NRBLK_ - 1)) ? 1u : 0u;
    }
    __syncthreads();
    if (!lastFlag) return;

    // ---- finalize: coherent snapshot, scan, trimmed mean ----
    unsigned int myc = atomicAdd(&gbins[t], 0u);
    __shared__ unsigned int scc[256];
    scc[t] = myc;
    __syncthreads();
    for (int off = 1; off < 256; off <<= 1) {
        unsigned int ac = (t >= off) ? scc[t - off] : 0u;
        __syncthreads();
        scc[t] += ac;
        __syncthreads();
    }
    unsigned int tot = scc[255];
    if (tot == 0u) { if (t == 0) out[0] = 0.0f; return; }
    unsigned int r4 = tot / 4u;        // dropped count
    unsigned int K = tot - r4;         // kept count (>=1)
    unsigned int cprev = (t == 0) ? 0u : scc[t - 1];
    if (scc[t] > r4 && cprev <= r4) {  // unique owner of the quantile bin
        double dropped = 0.0;
        for (int j = 0; j < t; ++j)
            dropped += (double)(scc[j] - (j == 0 ? 0u : scc[j - 1]))
                       * (((double)j + 0.5) / (double)BINSCALE_);
        dropped += (double)(r4 - cprev) * (((double)t + 0.5) / (double)BINSCALE_);
        double ts = atomicAdd(gsum, 0.0);   // coherent read of exact total
        out[0] = (float)((ts - dropped) / (double)K);
    }
}

extern "C" void kernel_launch(void* const* d_in, const int* in_sizes, int n_in,
                              void* d_out, int out_size, void* d_ws, size_t ws_size,
                              hipStream_t stream)
{
    const float* pred = (const float*)d_in[0];
    const float* targ = (const float*)d_in[1];
    // d_in[2] = mask: unused (only used in host-side index sampling)
    const float* intr = (const float*)d_in[3];
    const int* p1 = (const int*)d_in[4];
    const int* p2 = (const int*)d_in[5];
    const int* p3 = (const int*)d_in[6];
    float* out = (float*)d_out;

    unsigned char* ws = (unsigned char*)d_ws;
    unsigned short* bhist = (unsigned short*)(ws + OFF_BHIST);
    float* bsum = (float*)(ws + OFF_BSUM);
    unsigned int* gbins = (unsigned int*)(ws + OFF_GBINS);
    double* gsum = (double*)(ws + OFF_GSUM);
    unsigned int* donecnt = (unsigned int*)(ws + OFF_DONE);

    compute_kernel<<<NBLK_, 256, 0, stream>>>(pred, targ, intr, p1, p2, p3,
                                              bhist, bsum, gbins, gsum, donecnt);
    reduce_kernel<<<NRBLK_, 256, 0, stream>>>(bhist, bsum, gbins, gsum, donecnt, out);
}

// Round 9
// 125.546 us; speedup vs baseline: 1.0401x; 1.0401x over previous
//
#include <hip/hip_runtime.h>

// Problem constants (match reference)
#define B_ 8
#define H_ 512
#define W_ 1024
#define HW_ (H_ * W_)
#define G_ 104857
#define TILE_ 512                           // triplets per block (2 per thread)
#define TILES_ ((G_ + TILE_ - 1) / TILE_)   // 205
#define NBLK_ (TILES_ * B_)                 // 1640
#define EPS_ 1e-6f
#define DCOS_ 0.867f
#define DDIFF_ 0.005f
#define DZ_ 1e-5f

// Count-only 256-bin histogram over loss in [0, 2*sqrt(3)=3.4641].
// Trimmed-quantile bin-center approximation: measured absmax 0.0 in R5-R8.
#define NBIN_ 256
#define BINSCALE_ 73.0f          // 3.4642*73 = 252.9 < 256

// Reduction kernel geometry
#define NRBLK_ 64
#define ROWS_PER_ ((NBLK_ + NRBLK_ - 1) / NRBLK_)   // 26

// ws layout. NO memset node: kernel1 writes bhist/bsum fully and block 0 of
// kernel1 zero-inits the small reduction scratch (kernel-boundary coherence).
#define OFF_BHIST 0                                  // NBLK_ x 256 u16
#define OFF_BSUM  (NBLK_ * NBIN_ * 2)                // NBLK_ f32
#define OFF_GBINS (OFF_BSUM + NBLK_ * 4)             // 256 u32
#define OFF_GSUM  (OFF_GBINS + NBIN_ * 4)            // f64 (8-aligned)
#define OFF_DONE  (OFF_GSUM + 8)                     // u32

struct F3 { float x, y, z; };
__device__ __forceinline__ F3 f3sub(F3 a, F3 b) { return {a.x - b.x, a.y - b.y, a.z - b.z}; }
__device__ __forceinline__ float f3dot(F3 a, F3 b) { return a.x * b.x + a.y * b.y + a.z * b.z; }
__device__ __forceinline__ F3 f3cross(F3 a, F3 b) {
    return {a.y * b.z - a.z * b.y, a.z * b.x - a.x * b.z, a.x * b.y - a.y * b.x};
}

// Measured-optimal shape (R7, 126us): 2 triplets/thread — 6 index loads +
// 12 depth gathers issued before any consumption (kernel is gather-latency
// bound: VALU <20%, HBM <10% every round). TPT=1 (R6) +8us; TPT=4 (R8)
// +4.6us (VGPR pressure + 3.2-blocks/CU tail quantization).
// blockIdx.x & 7 = image -> image's depth data stays on one XCD's L2
// (FETCH 143->32MB measured in R2).
// No global atomics (R5: contended global atomics cost ~90us); histogram
// leaves as a coalesced non-atomic u16 store.
__global__ void __launch_bounds__(256)
compute_kernel(const float* __restrict__ pred, const float* __restrict__ targ,
               const float* __restrict__ intr,
               const int* __restrict__ p1, const int* __restrict__ p2,
               const int* __restrict__ p3,
               unsigned short* __restrict__ bhist, float* __restrict__ bsum,
               unsigned int* __restrict__ gbins, double* __restrict__ gsum,
               unsigned int* __restrict__ donecnt)
{
    __shared__ unsigned int hc[NBIN_];
    const int t = threadIdx.x;
    hc[t] = 0u;
    __syncthreads();

    const int img = blockIdx.x & 7;
    const int base = (blockIdx.x >> 3) * TILE_;

    const float fx = intr[img * 9 + 0];  // fx used for both x and y (per ref)
    const float u0 = intr[img * 9 + 2];
    const float v0 = intr[img * 9 + 5];
    const float invf = 1.0f / fx;
    const float* tb = targ + (size_t)img * HW_;
    const float* pb = pred + (size_t)img * HW_;
    const int goff = img * G_;

    // ---- all loads hoisted: 6 coalesced index loads, 12 gathers in flight ----
    const int gA = base + t;              // always < G_ (204*512+255 < 104857)
    const int gB = base + 256 + t;
    const bool inB = gB < G_;
    int a1 = p1[goff + gA], a2 = p2[goff + gA], a3 = p3[goff + gA];
    int b1 = inB ? p1[goff + gB] : 0;
    int b2 = inB ? p2[goff + gB] : 0;
    int b3 = inB ? p3[goff + gB] : 0;
    float tA1 = tb[a1], tA2 = tb[a2], tA3 = tb[a3];
    float pA1 = pb[a1], pA2 = pb[a2], pA3 = pb[a3];
    float tB1 = tb[b1], tB2 = tb[b2], tB3 = tb[b3];
    float pB1 = pb[b1], pB2 = pb[b2], pB3 = pb[b3];

    auto tri = [&](int i1, int i2, int i3, float dt1, float dt2, float dt3,
                   float dp1, float dp2, float dp3, float& loss) -> bool {
        auto mk = [&](int i, float d) -> F3 {
            float u = (float)(i & (W_ - 1));
            float v = (float)(i >> 10);
            return F3{(u - u0) * d * invf, (v - v0) * d * invf, d};
        };
        F3 G1 = mk(i1, dt1), G2 = mk(i2, dt2), G3 = mk(i3, dt3);
        F3 P1 = mk(i1, dp1), P2 = mk(i2, dp2), P3 = mk(i3, dp3);

        // ---- filter_mask on GT groups (division-free comparisons) ----
        F3 d12 = f3sub(G2, G1), d13 = f3sub(G3, G1), d23 = f3sub(G3, G2);
        float e11 = f3dot(d12, d12), e22 = f3dot(d13, d13), e33 = f3dot(d23, d23);
        float e12 = f3dot(d12, d13), e13 = f3dot(d12, d23), e23 = f3dot(d13, d23);
        float q1 = sqrtf(e11), q2 = sqrtf(e22), q3 = sqrtf(e33);
        int cnt = 0;
        cnt += (e11 > DCOS_ * (q1 * q1 + EPS_)) ? 1 : 0;
        cnt += (e22 > DCOS_ * (q2 * q2 + EPS_)) ? 1 : 0;
        cnt += (e33 > DCOS_ * (q3 * q3 + EPS_)) ? 1 : 0;
        cnt += (fabsf(e12) > DCOS_ * (q1 * q2 + EPS_)) ? 2 : 0;  // symmetric off-diag
        cnt += (fabsf(e13) > DCOS_ * (q1 * q3 + EPS_)) ? 2 : 0;
        cnt += (fabsf(e23) > DCOS_ * (q2 * q3 + EPS_)) ? 2 : 0;
        bool mask_cos = cnt > 3;
        bool mask_pad = (G1.z > DZ_) && (G2.z > DZ_) && (G3.z > DZ_);
        bool mx = (fabsf(d12.x) < DDIFF_) || (fabsf(d13.x) < DDIFF_) || (fabsf(d23.x) < DDIFF_);
        bool my = (fabsf(d12.y) < DDIFF_) || (fabsf(d13.y) < DDIFF_) || (fabsf(d23.y) < DDIFF_);
        bool mz = (fabsf(d12.z) < DDIFF_) || (fabsf(d13.z) < DDIFF_) || (fabsf(d23.z) < DDIFF_);
        bool valid = mask_pad && !((mx && my && mz) || mask_cos);
        if (!valid) { loss = 0.0f; return false; }

        // faithful replication of the reference's boolean-mask broadcast quirk
        bool c0 = (P1.z == 0.0f), c1 = (P2.z == 0.0f), c2 = (P3.z == 0.0f);
        if (c0) { P1.x = 1e-4f; P2.x = 1e-4f; P3.x = 1e-4f; }
        if (c1) { P1.y = 1e-4f; P2.y = 1e-4f; P3.y = 1e-4f; }
        if (c2) { P1.z = 1e-4f; P2.z = 1e-4f; P3.z = 1e-4f; }

        auto vnormal = [](F3 A, F3 Bp, F3 C) -> F3 {
            F3 a = f3sub(Bp, A), c = f3sub(C, A);
            F3 n = f3cross(a, c);
            float d = f3dot(n, n);
            float r = (d > 0.0f) ? rsqrtf(d) : 0.0f;  // n==0 -> 0/EPS==0 in ref
            return F3{n.x * r, n.y * r, n.z * r};
        };
        F3 ng = vnormal(G1, G2, G3);
        F3 nd = vnormal(P1, P2, P3);
        loss = fabsf(ng.x - nd.x) + fabsf(ng.y - nd.y) + fabsf(ng.z - nd.z);
        return true;
    };

    float lA = 0.0f, lB = 0.0f;
    bool vA = tri(a1, a2, a3, tA1, tA2, tA3, pA1, pA2, pA3, lA);
    bool vB = inB && tri(b1, b2, b3, tB1, tB2, tB3, pB1, pB2, pB3, lB);

    if (vA) atomicAdd(&hc[min((int)(lA * BINSCALE_), NBIN_ - 1)], 1u);
    if (vB) atomicAdd(&hc[min((int)(lB * BINSCALE_), NBIN_ - 1)], 1u);

    // exact loss sum: wave shuffle -> block -> one f32 store (no atomics)
    float lsum = (vA ? lA : 0.0f) + (vB ? lB : 0.0f);
    for (int off = 32; off > 0; off >>= 1) lsum += __shfl_down(lsum, off, 64);
    __shared__ float wsum[4];
    if ((t & 63) == 0) wsum[t >> 6] = lsum;
    __syncthreads();
    if (t == 0) bsum[blockIdx.x] = wsum[0] + wsum[1] + wsum[2] + wsum[3];

    // non-atomic coalesced histogram dump (u16: block max count 512 fits)
    bhist[(size_t)blockIdx.x * NBIN_ + t] = (unsigned short)hc[t];

    // block 0 zero-inits kernel2's scratch (kernel-boundary coherence)
    if (blockIdx.x == 0) {
        gbins[t] = 0u;
        if (t == 0) { *gsum = 0.0; *donecnt = 0u; }
    }
}

// 64 blocks: column-sum the 1640x256 u16 block-histograms in registers
// (coalesced 512B rows, L2-resident), flush 16K well-spread global atomics;
// block 0 reduces the block sums; last-done block computes the trimmed mean.
__global__ void __launch_bounds__(256)
reduce_kernel(const unsigned short* __restrict__ bhist, const float* __restrict__ bsum,
              unsigned int* __restrict__ gbins, double* __restrict__ gsum,
              unsigned int* __restrict__ donecnt, float* __restrict__ out)
{
    const int t = threadIdx.x;
    const int r0 = blockIdx.x * ROWS_PER_;
    const int r1 = min(NBLK_, r0 + ROWS_PER_);
    unsigned int acc = 0;
    for (int r = r0; r < r1; ++r) acc += (unsigned int)bhist[(size_t)r * NBIN_ + t];
    if (acc) atomicAdd(&gbins[t], acc);

    if (blockIdx.x == 0) {  // exact total sum
        double ls = 0.0;
        for (int i = t; i < NBLK_; i += 256) ls += (double)bsum[i];
        for (int off = 32; off > 0; off >>= 1) ls += __shfl_down(ls, off, 64);
        __shared__ double ws[4];
        if ((t & 63) == 0) ws[t >> 6] = ls;
        __syncthreads();
        if (t == 0) atomicAdd(gsum, ws[0] + ws[1] + ws[2] + ws[3]);
    }

    __shared__ unsigned int lastFlag;
    __syncthreads();
    if (t == 0) {
        __threadfence();
        lastFlag = (atomicAdd(donecnt, 1u) == (unsigned int)(NRBLK_ - 1)) ? 1u : 0u;
    }
    __syncthreads();
    if (!lastFlag) return;

    // ---- finalize: coherent snapshot, scan, trimmed mean ----
    unsigned int myc = atomicAdd(&gbins[t], 0u);
    __shared__ unsigned int scc[256];
    scc[t] = myc;
    __syncthreads();
    for (int off = 1; off < 256; off <<= 1) {
        unsigned int ac = (t >= off) ? scc[t - off] : 0u;
        __syncthreads();
        scc[t] += ac;
        __syncthreads();
    }
    unsigned int tot = scc[255];
    if (tot == 0u) { if (t == 0) out[0] = 0.0f; return; }
    unsigned int r4 = tot / 4u;        // dropped count
    unsigned int K = tot - r4;         // kept count (>=1)
    unsigned int cprev = (t == 0) ? 0u : scc[t - 1];
    if (scc[t] > r4 && cprev <= r4) {  // unique owner of the quantile bin
        double dropped = 0.0;
        for (int j = 0; j < t; ++j)
            dropped += (double)(scc[j] - (j == 0 ? 0u : scc[j - 1]))
                       * (((double)j + 0.5) / (double)BINSCALE_);
        dropped += (double)(r4 - cprev) * (((double)t + 0.5) / (double)BINSCALE_);
        double ts = atomicAdd(gsum, 0.0);   // coherent read of exact total
        out[0] = (float)((ts - dropped) / (double)K);
    }
}

extern "C" void kernel_launch(void* const* d_in, const int* in_sizes, int n_in,
                              void* d_out, int out_size, void* d_ws, size_t ws_size,
                              hipStream_t stream)
{
    const float* pred = (const float*)d_in[0];
    const float* targ = (const float*)d_in[1];
    // d_in[2] = mask: unused (only used in host-side index sampling)
    const float* intr = (const float*)d_in[3];
    const int* p1 = (const int*)d_in[4];
    const int* p2 = (const int*)d_in[5];
    const int* p3 = (const int*)d_in[6];
    float* out = (float*)d_out;

    unsigned char* ws = (unsigned char*)d_ws;
    unsigned short* bhist = (unsigned short*)(ws + OFF_BHIST);
    float* bsum = (float*)(ws + OFF_BSUM);
    unsigned int* gbins = (unsigned int*)(ws + OFF_GBINS);
    double* gsum = (double*)(ws + OFF_GSUM);
    unsigned int* donecnt = (unsigned int*)(ws + OFF_DONE);

    compute_kernel<<<NBLK_, 256, 0, stream>>>(pred, targ, intr, p1, p2, p3,
                                              bhist, bsum, gbins, gsum, donecnt);
    reduce_kernel<<<NRBLK_, 256, 0, stream>>>(bhist, bsum, gbins, gsum, donecnt, out);
}